// Round 3
// baseline (684.953 us; speedup 1.0000x reference)
//
#include <hip/hip_runtime.h>
#include <hip/hip_bf16.h>

// hierarch_sep_loss: preds [2, N, 100] fp32 probs, labs [2, N] int, cen [2, N] int
// out[0] = sum over mods of:
//   (n_u/N) * (-sum_{cen==0} log(p[i,lab_i]+EPS) / max(1,n_u))
// + (n_c/N) * (-sum_{cen==1} log(sum_{j>lab0_i} p[i,j]+EPS) / max(1,n_c)) * 0.5
//
// R2 post-mortem: LDS-staged tiles were convoy-bound (load->drain->barrier->scan
// per tile; 785 GB/s, VALUBusy 9%). R3: no LDS, no barriers in the main loop.
// 4 lanes per row; lane q loads float4s at rowp + 16q + 64k (k=0..5) -> every
// wave-instruction touches whole 64B lines fully consumed in that instruction
// (perfectly coalesced, exactly 400B/row), plus one shared tail float4 (floats
// 96..99, contributions taken only by q==0). 7 independent loads/lane give
// ~112 KB in flight per CU at 16 waves/CU -- pure streaming.

#define HSL_EPS 1e-10f

__global__ __launch_bounds__(256, 4) void hsl_main(
    const float* __restrict__ preds,
    const int*   __restrict__ labs,
    const int*   __restrict__ cen,
    double*       __restrict__ sums,   // [4]: usum0, csum0, usum1, csum1
    unsigned int* __restrict__ cnts,   // [4]: ucnt0, ccnt0, ucnt1, ccnt1
    long long N)
{
    const long long R = 2LL * N;
    const int q = threadIdx.x & 3;               // lane's quarter of the row
    const long long g0 = ((long long)blockIdx.x * blockDim.x + threadIdx.x) >> 2;
    const long long ng = ((long long)gridDim.x * blockDim.x) >> 2;

    double usum[2] = {0.0, 0.0};
    double csum[2] = {0.0, 0.0};
    unsigned int ucnt[2] = {0u, 0u};
    unsigned int ccnt[2] = {0u, 0u};

    for (long long r = g0; r < R; r += ng) {
        const int m = (r >= N) ? 1 : 0;
        const long long i0 = r - (long long)m * N;
        const int lab = labs[r];
        const int t1  = labs[i0] + 1;            // censored: sum over j >= t1
        const int c   = cen[r];
        const float* rowp = preds + r * 100;

        // lane q owns floats j = 4q + 16k + e (k=0..5, e=0..3): bytes 16q+64k,
        // i.e. each instruction reads 16 whole 64B lines across 16 rows.
        float4 v[7];
        #pragma unroll
        for (int k = 0; k < 6; ++k)
            v[k] = *(const float4*)(rowp + 4 * q + 16 * k);
        v[6] = *(const float4*)(rowp + 96);      // tail floats 96..99 (all q load same 16B)

        float sp = 0.0f, gp = 0.0f;
        const int jb = 4 * q;
        #pragma unroll
        for (int k = 0; k < 6; ++k) {
            #pragma unroll
            for (int e = 0; e < 4; ++e) {
                const int j = jb + 16 * k + e;   // jb runtime, rest compile-time
                const float p = ((const float*)&v[k])[e];
                sp += (j >= t1) ? p : 0.0f;
                gp  = (j == lab) ? p : gp;
            }
        }
        if (q == 0) {                            // tail contributions once per row
            #pragma unroll
            for (int e = 0; e < 4; ++e) {
                const int j = 96 + e;
                const float p = ((const float*)&v[6])[e];
                sp += (j >= t1) ? p : 0.0f;
                gp  = (j == lab) ? p : gp;
            }
        }

        // combine the 4 quarter-partials (lanes 4g..4g+3 adjacent)
        sp += __shfl_xor(sp, 1, 64); sp += __shfl_xor(sp, 2, 64);
        gp += __shfl_xor(gp, 1, 64); gp += __shfl_xor(gp, 2, 64);

        if (q == 0) {
            if (c == 0) { usum[m] += (double)logf(gp + HSL_EPS); ucnt[m]++; }
            else        { csum[m] += (double)logf(sp + HSL_EPS); ccnt[m]++; }
        }
    }

    // ---- wave shuffle reduction -> block LDS -> one atomic set per block ----
    #pragma unroll
    for (int off = 32; off > 0; off >>= 1) {
        usum[0] += __shfl_down(usum[0], off, 64);
        csum[0] += __shfl_down(csum[0], off, 64);
        usum[1] += __shfl_down(usum[1], off, 64);
        csum[1] += __shfl_down(csum[1], off, 64);
        ucnt[0] += __shfl_down(ucnt[0], off, 64);
        ccnt[0] += __shfl_down(ccnt[0], off, 64);
        ucnt[1] += __shfl_down(ucnt[1], off, 64);
        ccnt[1] += __shfl_down(ccnt[1], off, 64);
    }

    __shared__ double sh_sums[4][4];
    __shared__ unsigned int sh_cnts[4][4];
    const int waveInBlk = threadIdx.x >> 6;
    const int lane = threadIdx.x & 63;
    if (lane == 0) {
        sh_sums[waveInBlk][0] = usum[0]; sh_sums[waveInBlk][1] = csum[0];
        sh_sums[waveInBlk][2] = usum[1]; sh_sums[waveInBlk][3] = csum[1];
        sh_cnts[waveInBlk][0] = ucnt[0]; sh_cnts[waveInBlk][1] = ccnt[0];
        sh_cnts[waveInBlk][2] = ucnt[1]; sh_cnts[waveInBlk][3] = ccnt[1];
    }
    __syncthreads();
    if (threadIdx.x == 0) {
        for (int slot = 0; slot < 4; ++slot) {
            double s = 0.0; unsigned int k = 0u;
            for (int w = 0; w < 4; ++w) { s += sh_sums[w][slot]; k += sh_cnts[w][slot]; }
            atomicAdd(&sums[slot], s);
            if (k) atomicAdd(&cnts[slot], k);
        }
    }
}

__global__ void hsl_final(const double* __restrict__ sums,
                          const unsigned int* __restrict__ cnts,
                          float* __restrict__ out, long long N)
{
    if (threadIdx.x == 0 && blockIdx.x == 0) {
        float total = 0.0f;
        const float n = (float)N;
        for (int m = 0; m < 2; ++m) {
            const float nu = (float)cnts[2 * m + 0];
            const float nc = (float)cnts[2 * m + 1];
            const float us = (float)sums[2 * m + 0];
            const float cs = (float)sums[2 * m + 1];
            const float uncen_loss = -us / fmaxf(1.0f, nu);
            const float cen_loss   = -cs / fmaxf(1.0f, nc);
            total += (nu / n) * uncen_loss + (nc / n) * cen_loss * 0.5f;
        }
        out[0] = total;
    }
}

extern "C" void kernel_launch(void* const* d_in, const int* in_sizes, int n_in,
                              void* d_out, int out_size, void* d_ws, size_t ws_size,
                              hipStream_t stream)
{
    const float* preds = (const float*)d_in[0];
    const int*   labs  = (const int*)d_in[1];
    const int*   cen   = (const int*)d_in[2];
    float* out = (float*)d_out;

    const long long N = (long long)(in_sizes[1] / 2);   // labs flat = 2*N; B=100 hardcoded

    double*       sums = (double*)d_ws;
    unsigned int* cnts = (unsigned int*)((char*)d_ws + 32);

    hipMemsetAsync(d_ws, 0, 48, stream);

    const int threads = 256;
    const int blocks  = 2048;      // 8 blocks/CU worth of waves; no LDS limit now
    hsl_main<<<blocks, threads, 0, stream>>>(preds, labs, cen, sums, cnts, N);
    hsl_final<<<1, 64, 0, stream>>>(sums, cnts, out, N);
}

// Round 4
// 528.591 us; speedup vs baseline: 1.2958x; 1.2958x over previous
//
#include <hip/hip_runtime.h>
#include <hip/hip_bf16.h>

// hierarch_sep_loss: preds [2, N, 100] fp32 probs, labs [2, N] int, cen [2, N] int
// out[0] = sum over mods of:
//   (n_u/N) * (-sum_{cen==0} log(p[i,lab_i]+EPS) / max(1,n_u))
// + (n_c/N) * (-sum_{cen==1} log(sum_{j>lab0_i} p[i,j]+EPS) / max(1,n_c)) * 0.5
//
// R3 post-mortem: streaming loop accounts for <15% of billed cycles; the
// structure-independent ~90% idle across R1/R2/R3 points at the epilogue:
// 2048-way atomicAdd(double) on 4 shared addresses = CAS-loop livelock tail.
// R4: zero atomics — per-block partial slots in d_ws + tiny reduce kernel.

#define HSL_EPS 1e-10f
#define NBLK 2048

__global__ __launch_bounds__(256, 4) void hsl_main(
    const float* __restrict__ preds,
    const int*   __restrict__ labs,
    const int*   __restrict__ cen,
    double*       __restrict__ bsums,  // [4][NBLK] per-block partials (or [4] atomic accums)
    unsigned int* __restrict__ bcnts,  // [4][NBLK]                    (or [4])
    long long N, int use_atomic)
{
    const long long R = 2LL * N;
    const int q = threadIdx.x & 3;               // lane's quarter of the row
    const long long g0 = ((long long)blockIdx.x * blockDim.x + threadIdx.x) >> 2;
    const long long ng = ((long long)gridDim.x * blockDim.x) >> 2;

    double usum[2] = {0.0, 0.0};
    double csum[2] = {0.0, 0.0};
    unsigned int ucnt[2] = {0u, 0u};
    unsigned int ccnt[2] = {0u, 0u};

    for (long long r = g0; r < R; r += ng) {
        const int m = (r >= N) ? 1 : 0;
        const long long i0 = r - (long long)m * N;
        const int lab = labs[r];
        const int t1  = labs[i0] + 1;            // censored: sum over j >= t1
        const int c   = cen[r];
        const float* rowp = preds + r * 100;

        // lane q owns floats j = 4q + 16k + e (k=0..5): whole 64B lines per instr
        float4 v[7];
        #pragma unroll
        for (int k = 0; k < 6; ++k)
            v[k] = *(const float4*)(rowp + 4 * q + 16 * k);
        v[6] = *(const float4*)(rowp + 96);      // tail floats 96..99

        float sp = 0.0f, gp = 0.0f;
        const int jb = 4 * q;
        #pragma unroll
        for (int k = 0; k < 6; ++k) {
            #pragma unroll
            for (int e = 0; e < 4; ++e) {
                const int j = jb + 16 * k + e;
                const float p = ((const float*)&v[k])[e];
                sp += (j >= t1) ? p : 0.0f;
                gp  = (j == lab) ? p : gp;
            }
        }
        if (q == 0) {
            #pragma unroll
            for (int e = 0; e < 4; ++e) {
                const int j = 96 + e;
                const float p = ((const float*)&v[6])[e];
                sp += (j >= t1) ? p : 0.0f;
                gp  = (j == lab) ? p : gp;
            }
        }

        sp += __shfl_xor(sp, 1, 64); sp += __shfl_xor(sp, 2, 64);
        gp += __shfl_xor(gp, 1, 64); gp += __shfl_xor(gp, 2, 64);

        if (q == 0) {
            if (c == 0) { usum[m] += (double)logf(gp + HSL_EPS); ucnt[m]++; }
            else        { csum[m] += (double)logf(sp + HSL_EPS); ccnt[m]++; }
        }
    }

    // ---- wave shuffle reduction -> block LDS -> ONE plain store per block ----
    #pragma unroll
    for (int off = 32; off > 0; off >>= 1) {
        usum[0] += __shfl_down(usum[0], off, 64);
        csum[0] += __shfl_down(csum[0], off, 64);
        usum[1] += __shfl_down(usum[1], off, 64);
        csum[1] += __shfl_down(csum[1], off, 64);
        ucnt[0] += __shfl_down(ucnt[0], off, 64);
        ccnt[0] += __shfl_down(ccnt[0], off, 64);
        ucnt[1] += __shfl_down(ucnt[1], off, 64);
        ccnt[1] += __shfl_down(ccnt[1], off, 64);
    }

    __shared__ double sh_sums[4][4];
    __shared__ unsigned int sh_cnts[4][4];
    const int waveInBlk = threadIdx.x >> 6;
    const int lane = threadIdx.x & 63;
    if (lane == 0) {
        sh_sums[waveInBlk][0] = usum[0]; sh_sums[waveInBlk][1] = csum[0];
        sh_sums[waveInBlk][2] = usum[1]; sh_sums[waveInBlk][3] = csum[1];
        sh_cnts[waveInBlk][0] = ucnt[0]; sh_cnts[waveInBlk][1] = ccnt[0];
        sh_cnts[waveInBlk][2] = ucnt[1]; sh_cnts[waveInBlk][3] = ccnt[1];
    }
    __syncthreads();
    if (threadIdx.x < 4) {
        const int slot = threadIdx.x;
        double s = 0.0; unsigned int k = 0u;
        for (int w = 0; w < 4; ++w) { s += sh_sums[w][slot]; k += sh_cnts[w][slot]; }
        if (use_atomic) {
            atomicAdd(&bsums[slot], s);
            if (k) atomicAdd(&bcnts[slot], k);
        } else {
            bsums[slot * NBLK + blockIdx.x] = s;   // plain coalesced-ish store
            bcnts[slot * NBLK + blockIdx.x] = k;
        }
    }
}

__global__ __launch_bounds__(256) void hsl_final(
    const double* __restrict__ bsums,
    const unsigned int* __restrict__ bcnts,
    float* __restrict__ out, long long N, int nblk)
{
    // nblk==0: bsums/bcnts are 4-entry global accumulators (atomic fallback).
    double s[4] = {0.0, 0.0, 0.0, 0.0};
    double kc[4] = {0.0, 0.0, 0.0, 0.0};
    if (nblk > 0) {
        for (int b = threadIdx.x; b < nblk; b += 256) {
            #pragma unroll
            for (int slot = 0; slot < 4; ++slot) {
                s[slot]  += bsums[slot * nblk + b];
                kc[slot] += (double)bcnts[slot * nblk + b];
            }
        }
    } else if (threadIdx.x == 0) {
        #pragma unroll
        for (int slot = 0; slot < 4; ++slot) {
            s[slot] = bsums[slot]; kc[slot] = (double)bcnts[slot];
        }
    }

    #pragma unroll
    for (int off = 32; off > 0; off >>= 1) {
        #pragma unroll
        for (int slot = 0; slot < 4; ++slot) {
            s[slot]  += __shfl_down(s[slot],  off, 64);
            kc[slot] += __shfl_down(kc[slot], off, 64);
        }
    }

    __shared__ double sh[4][8];
    const int waveInBlk = threadIdx.x >> 6;
    const int lane = threadIdx.x & 63;
    if (lane == 0) {
        #pragma unroll
        for (int slot = 0; slot < 4; ++slot) {
            sh[waveInBlk][slot]     = s[slot];
            sh[waveInBlk][4 + slot] = kc[slot];
        }
    }
    __syncthreads();
    if (threadIdx.x == 0) {
        double fs[4], fk[4];
        #pragma unroll
        for (int slot = 0; slot < 4; ++slot) {
            fs[slot] = sh[0][slot] + sh[1][slot] + sh[2][slot] + sh[3][slot];
            fk[slot] = sh[0][4+slot] + sh[1][4+slot] + sh[2][4+slot] + sh[3][4+slot];
        }
        float total = 0.0f;
        const float n = (float)N;
        for (int m = 0; m < 2; ++m) {
            const float nu = (float)fk[2 * m + 0];
            const float nc = (float)fk[2 * m + 1];
            const float us = (float)fs[2 * m + 0];
            const float cs = (float)fs[2 * m + 1];
            const float uncen_loss = -us / fmaxf(1.0f, nu);
            const float cen_loss   = -cs / fmaxf(1.0f, nc);
            total += (nu / n) * uncen_loss + (nc / n) * cen_loss * 0.5f;
        }
        out[0] = total;
    }
}

extern "C" void kernel_launch(void* const* d_in, const int* in_sizes, int n_in,
                              void* d_out, int out_size, void* d_ws, size_t ws_size,
                              hipStream_t stream)
{
    const float* preds = (const float*)d_in[0];
    const int*   labs  = (const int*)d_in[1];
    const int*   cen   = (const int*)d_in[2];
    float* out = (float*)d_out;

    const long long N = (long long)(in_sizes[1] / 2);   // labs flat = 2*N; B=100 hardcoded

    const size_t need = (size_t)4 * NBLK * sizeof(double)
                      + (size_t)4 * NBLK * sizeof(unsigned int);

    if (ws_size >= need) {
        // no-atomic path: per-block partial slots, written unconditionally
        double*       bsums = (double*)d_ws;
        unsigned int* bcnts = (unsigned int*)((char*)d_ws + (size_t)4 * NBLK * sizeof(double));
        hsl_main<<<NBLK, 256, 0, stream>>>(preds, labs, cen, bsums, bcnts, N, 0);
        hsl_final<<<1, 256, 0, stream>>>(bsums, bcnts, out, N, NBLK);
    } else {
        // fallback: old atomic path into 48 B of ws (poisoned -> must zero)
        double*       sums = (double*)d_ws;
        unsigned int* cnts = (unsigned int*)((char*)d_ws + 32);
        hipMemsetAsync(d_ws, 0, 48, stream);
        hsl_main<<<NBLK, 256, 0, stream>>>(preds, labs, cen, sums, cnts, N, 1);
        hsl_final<<<1, 256, 0, stream>>>(sums, cnts, out, N, 0);
    }
}